// Round 1
// baseline (137.122 us; speedup 1.0000x reference)
//
#include <hip/hip_runtime.h>

// DepthwiseTemporalConv: I[n,c,t] = x_flat[n*16384 + c*64 + t], n in [0,4096), c in [0,256), t in [0,64)
// Y[n,c,t] = sum_{k=0}^{63-t} I[n,c,t+k] * W[c,k]
// out_flat[(n>>10)*16777216 + c*65536 + t*1024 + (n&1023)] = Y[n,c,t]

constexpr int Cc = 256;
constexpr int Tt = 64;
constexpr int Kk = 64;
constexpr int CT = Cc * Tt;                        // 16384
constexpr int NC_TILE = 4;                         // c per block
constexpr int NN_TILE = 64;                        // n per block
constexpr int CHUNK_BYTES = NC_TILE * Tt * 4;      // 1024 B per n-chunk
constexpr int CHUNK_STRIDE = CHUNK_BYTES + 16;     // pad -> conflict-free b128 reads
constexpr int LDS_BYTES = NN_TILE * CHUNK_STRIDE;  // 66560 B

__global__ __launch_bounds__(256, 2)
void DepthwiseTemporalConv_24962349924982_kernel(const float* __restrict__ x,
                                                 const float* __restrict__ w,
                                                 float* __restrict__ out) {
    __shared__ __align__(16) char lds[LDS_BYTES];
    const int tid  = threadIdx.x;
    const int lane = tid & 63;
    const int wv   = tid >> 6;

    const int n_tile = blockIdx.x & 63;   // 64 n-tiles
    const int c_tile = blockIdx.x >> 6;   // 64 c-tiles
    const int n0 = n_tile * NN_TILE;
    const int c0 = c_tile * NC_TILE;

    // ---- stage 64 n-chunks (1 KiB each, contiguous in global) into LDS.
    // Wave wv handles chunks i = 4*it + wv; LDS dest is wave-uniform base + lane*16.
    for (int it = 0; it < 16; ++it) {
        const int i = (it << 2) + wv;
        const float* gsrc = x + (size_t)(n0 + i) * CT + c0 * Tt + lane * 4;
        __builtin_amdgcn_global_load_lds(
            (const __attribute__((address_space(1))) void*)gsrc,
            (__attribute__((address_space(3))) void*)(lds + i * CHUNK_STRIDE),
            16, 0, 0);
    }

    // ---- weights: warp-uniform c = c0 + wv, 64 floats -> registers (L2-resident)
    float wr[Kk];
    {
        const float4* wp = (const float4*)(w + (size_t)(c0 + wv) * Kk);
        #pragma unroll
        for (int m = 0; m < 16; ++m) {
            const float4 v = wp[m];
            wr[4*m+0] = v.x; wr[4*m+1] = v.y; wr[4*m+2] = v.z; wr[4*m+3] = v.w;
        }
    }

    __syncthreads();   // drains vmcnt (global_load_lds) before LDS reads

    // ---- this thread's row (n0+lane, c0+wv): 64 floats -> registers
    float xr[Tt];
    {
        const char* base = lds + lane * CHUNK_STRIDE + wv * (Tt * 4);
        #pragma unroll
        for (int m = 0; m < 16; ++m) {
            const float4 v = *(const float4*)(base + m * 16);
            xr[4*m+0] = v.x; xr[4*m+1] = v.y; xr[4*m+2] = v.z; xr[4*m+3] = v.w;
        }
    }

    // ---- triangular suffix correlation, fully unrolled (static reg indices),
    // 2 accumulator chains to cover FMA latency. Stores are wave-coalesced
    // (lane -> consecutive n within h*w).
    const int n = n0 + lane;
    const int c = c0 + wv;
    float* obase = out + (size_t)(n >> 10) * (Cc * Tt * 1024)
                       + (size_t)c * (Tt * 1024) + (n & 1023);
    #pragma unroll
    for (int t = 0; t < Tt; ++t) {
        const int len = Tt - t;
        float a0 = 0.f, a1 = 0.f;
        #pragma unroll
        for (int k = 0; k + 1 < len; k += 2) {
            a0 = fmaf(xr[t + k],     wr[k],     a0);
            a1 = fmaf(xr[t + k + 1], wr[k + 1], a1);
        }
        if (len & 1) a0 = fmaf(xr[Tt - 1], wr[len - 1], a0);
        obase[(size_t)t * 1024] = a0 + a1;
    }
}

extern "C" void kernel_launch(void* const* d_in, const int* in_sizes, int n_in,
                              void* d_out, int out_size, void* d_ws, size_t ws_size,
                              hipStream_t stream) {
    const float* x = (const float*)d_in[0];
    const float* w = (const float*)d_in[1];
    float* out = (float*)d_out;
    // grid: 64 n-tiles x 64 c-tiles
    DepthwiseTemporalConv_24962349924982_kernel<<<dim3(4096), dim3(256), 0, stream>>>(x, w, out);
}